// Round 1
// baseline (119.820 us; speedup 1.0000x reference)
//
#include <hip/hip_runtime.h>
#include <math.h>

#define BH 4
#define HH 512
#define WW 512
#define NPIX (BH * HH * WW)

// ws layout:
//   [0]                : float accum
//   [16 .. 16+4*BH)    : int flags[BH] (has_fg per batch)
//   [256 .. 256+4MB)   : int gup[NPIX]   (y - last_fg_row_above, unclamped)
//   [256+4MB .. +8MB)  : int gdn[NPIX]   (next_fg_row_below - y, unclamped)

__global__ void edt_col_scan(const int* __restrict__ tgt,
                             int* __restrict__ gup,
                             int* __restrict__ gdn,
                             int* __restrict__ flags) {
    const int colBlk = blockIdx.x;              // b*(WW/64) + xt
    const int b = colBlk / (WW / 64);
    const int x = (colBlk % (WW / 64)) * 64 + threadIdx.x;
    const int* t = tgt + (size_t)b * HH * WW + x;

    if (blockIdx.y == 0) {
        // downward pass: distance to nearest fg row at-or-above
        int last = -1024;                        // matches ref sentinel -big
        int any = 0;
        int* o = gup + (size_t)b * HH * WW + x;
        #pragma unroll 8
        for (int y = 0; y < HH; ++y) {
            int v = t[(size_t)y * WW];
            if (v > 0) { last = y; any = 1; }
            o[(size_t)y * WW] = y - last;
        }
        if (any) atomicOr(&flags[b], 1);
    } else {
        // upward pass: distance to nearest fg row at-or-below
        int nxt = 3 * 1024;                      // matches ref sentinel 3*big
        int* o = gdn + (size_t)b * HH * WW + x;
        #pragma unroll 8
        for (int y = HH - 1; y >= 0; --y) {
            int v = t[(size_t)y * WW];
            if (v > 0) nxt = y;
            o[(size_t)y * WW] = nxt - y;
        }
    }
}

__global__ void edt_row_loss(const float* __restrict__ pred,
                             const int* __restrict__ gup,
                             const int* __restrict__ gdn,
                             const int* __restrict__ flags,
                             float* __restrict__ accum) {
    const int row = blockIdx.x;                 // b*HH + y
    const int b = row >> 9;                     // HH == 512
    const int base = row * WW;
    const int tid = threadIdx.x;                // 256 threads

    __shared__ float sg2[WW];
    for (int j = tid; j < WW; j += 256) {
        int g = min(min(gup[base + j], gdn[base + j]), 1024);
        float gf = (float)g;
        sg2[j] = gf * gf;
    }
    __syncthreads();

    // brute-force exact 1D transform: dist2[x] = min_j (x-j)^2 + g2[j]
    const float x0 = (float)tid;
    const float x1 = (float)(tid + 256);
    float m0 = 3.4e38f, m1 = 3.4e38f;
    float d0 = x0, d1 = x1;                     // d = x - j, decremented
    #pragma unroll 8
    for (int j = 0; j < WW; ++j) {
        float g = sg2[j];                       // broadcast, conflict-free
        m0 = fminf(m0, fmaf(d0, d0, g));
        m1 = fminf(m1, fmaf(d1, d1, g));
        d0 -= 1.0f;
        d1 -= 1.0f;
    }

    float p0 = 1.0f / (1.0f + expf(-pred[base + tid]));
    float p1 = 1.0f / (1.0f + expf(-pred[base + tid + 256]));
    float fg = flags[b] ? 1.0f : 0.0f;
    float val = fg * (p0 * sqrtf(m0) + p1 * sqrtf(m1)) * (1.0f / (float)NPIX);

    // wave (64-lane) reduce, then cross-wave via LDS
    #pragma unroll
    for (int off = 32; off > 0; off >>= 1)
        val += __shfl_down(val, off);
    __shared__ float swave[4];
    if ((tid & 63) == 0) swave[tid >> 6] = val;
    __syncthreads();
    if (tid == 0)
        atomicAdd(accum, swave[0] + swave[1] + swave[2] + swave[3]);
}

__global__ void finalize(const float* __restrict__ accum, float* __restrict__ out) {
    out[0] = accum[0];
}

extern "C" void kernel_launch(void* const* d_in, const int* in_sizes, int n_in,
                              void* d_out, int out_size, void* d_ws, size_t ws_size,
                              hipStream_t stream) {
    const float* pred = (const float*)d_in[0];
    const int* tgt = (const int*)d_in[1];
    float* out = (float*)d_out;

    char* ws = (char*)d_ws;
    float* accum = (float*)ws;
    int* flags = (int*)(ws + 16);
    int* gup = (int*)(ws + 256);
    int* gdn = (int*)(ws + 256 + (size_t)NPIX * sizeof(int));

    hipMemsetAsync(ws, 0, 256, stream);

    dim3 g1(BH * (WW / 64), 2);
    edt_col_scan<<<g1, 64, 0, stream>>>(tgt, gup, gdn, flags);
    edt_row_loss<<<BH * HH, 256, 0, stream>>>(pred, gup, gdn, flags, accum);
    finalize<<<1, 1, 0, stream>>>(accum, out);
}

// Round 4
// 70.300 us; speedup vs baseline: 1.7044x; 1.7044x over previous
//
#include <hip/hip_runtime.h>
#include <math.h>

#define BH 4
#define HH 512
#define WW 512
#define NPIX (BH * HH * WW)
#define NTILES 8               // 512 cols / 64 lanes
#define NSEG 16                // 512 rows / 32
#define SEGROWS 32

// ws layout:
//   [0    .. 128)   : int blockAny[32]     (per col-scan block: any fg)
//   [128  .. 8320)  : float rowSum[2048]   (per row-loss block partial)
//   [16K  .. +4MB)  : float g2[NPIX]       (clamped squared 1D distances)

__global__ __launch_bounds__(1024) void edt_col_scan(
    const int* __restrict__ tgt, float* __restrict__ g2,
    int* __restrict__ blockAny) {
    const int b    = blockIdx.x >> 3;
    const int xt   = blockIdx.x & 7;
    const int lane = threadIdx.x & 63;
    const int wave = threadIdx.x >> 6;            // 0..15
    const int x    = xt * 64 + lane;
    const int y0   = wave * SEGROWS;
    const int* t   = tgt + b * HH * WW + x;
    float* gp      = g2  + b * HH * WW + x;

    // load this wave's 32-row segment (coalesced 256B per row, all in flight)
    int v[SEGROWS];
    #pragma unroll
    for (int i = 0; i < SEGROWS; ++i)
        v[i] = t[(y0 + i) * WW];

    // per-segment last/first foreground row (absolute), sentinels match ref
    int segLast = -1024, segFirst = 3 * 1024;
    #pragma unroll
    for (int i = 0; i < SEGROWS; ++i)
        if (v[i] > 0) segLast = y0 + i;
    #pragma unroll
    for (int i = SEGROWS - 1; i >= 0; --i)
        if (v[i] > 0) segFirst = y0 + i;

    __shared__ int sLast[NSEG][64];
    __shared__ int sFirst[NSEG][64];
    __shared__ int sAny[NSEG];
    sLast[wave][lane]  = segLast;
    sFirst[wave][lane] = segFirst;
    unsigned long long bal = __ballot(segLast >= 0);
    if (lane == 0) sAny[wave] = (bal != 0ull);
    __syncthreads();

    // carry-in from other segments of this column
    int carryLast = -1024;
    for (int s = 0; s < wave; ++s)
        carryLast = max(carryLast, sLast[s][lane]);
    int carryFirst = 3 * 1024;
    for (int s = wave + 1; s < NSEG; ++s)
        carryFirst = min(carryFirst, sFirst[s][lane]);

    // forward: distance to last fg at-or-above
    int gup[SEGROWS];
    int last = carryLast;
    #pragma unroll
    for (int i = 0; i < SEGROWS; ++i) {
        int y = y0 + i;
        if (v[i] > 0) last = y;
        gup[i] = y - last;
    }
    // backward: combine with distance to next fg at-or-below, clamp, emit g^2
    int nxt = carryFirst;
    #pragma unroll
    for (int i = SEGROWS - 1; i >= 0; --i) {
        int y = y0 + i;
        if (v[i] > 0) nxt = y;
        int g = min(min(gup[i], nxt - y), 1024);
        float gf = (float)g;
        gp[y * WW] = gf * gf;
    }

    if (threadIdx.x == 0) {
        int a = 0;
        #pragma unroll
        for (int s = 0; s < NSEG; ++s) a |= sAny[s];
        blockAny[blockIdx.x] = a;
    }
}

__global__ __launch_bounds__(256) void edt_row_loss(
    const float* __restrict__ pred, const float* __restrict__ g2,
    float* __restrict__ rowSum) {
    const int row  = blockIdx.x;                  // b*HH + y
    const int base = row * WW;
    const int tid  = threadIdx.x;                 // 256

    __shared__ float sg2[WW];
    sg2[tid]       = g2[base + tid];
    sg2[tid + 256] = g2[base + tid + 256];
    __syncthreads();

    float acc = 0.0f;
    #pragma unroll
    for (int k = 0; k < 2; ++k) {
        const int x = tid + k * 256;
        float m = sg2[x];                         // j == x candidate
        // exact expanding scan: farther j cannot beat m once r^2 >= m
        for (int r = 1; r < WW; ++r) {
            float r2 = (float)(r * r);
            if (r2 >= m) break;
            int jl = x - r, jr = x + r;
            if (jl >= 0) m = fminf(m, sg2[jl] + r2);
            if (jr < WW) m = fminf(m, sg2[jr] + r2);
            if (jl < 0 && jr >= WW) break;
        }
        float p = 1.0f / (1.0f + expf(-pred[base + x]));
        acc += p * sqrtf(m);
    }

    #pragma unroll
    for (int off = 32; off > 0; off >>= 1)
        acc += __shfl_down(acc, off);
    __shared__ float sw[4];
    if ((tid & 63) == 0) sw[tid >> 6] = acc;
    __syncthreads();
    if (tid == 0) rowSum[row] = sw[0] + sw[1] + sw[2] + sw[3];
}

__global__ __launch_bounds__(256) void finalize(
    const float* __restrict__ rowSum, const int* __restrict__ blockAny,
    float* __restrict__ out) {
    const int tid = threadIdx.x;
    __shared__ float sflag[BH];
    if (tid < BH) {
        int a = 0;
        #pragma unroll
        for (int i = 0; i < NTILES; ++i) a |= blockAny[tid * NTILES + i];
        sflag[tid] = a ? 1.0f : 0.0f;
    }
    __syncthreads();
    float acc = 0.0f;
    for (int i = tid; i < BH * HH; i += 256)
        acc += rowSum[i] * sflag[i >> 9];
    #pragma unroll
    for (int off = 32; off > 0; off >>= 1)
        acc += __shfl_down(acc, off);
    __shared__ float sw[4];
    if ((tid & 63) == 0) sw[tid >> 6] = acc;
    __syncthreads();
    if (tid == 0) out[0] = (sw[0] + sw[1] + sw[2] + sw[3]) * (1.0f / (float)NPIX);
}

extern "C" void kernel_launch(void* const* d_in, const int* in_sizes, int n_in,
                              void* d_out, int out_size, void* d_ws, size_t ws_size,
                              hipStream_t stream) {
    const float* pred = (const float*)d_in[0];
    const int* tgt    = (const int*)d_in[1];
    float* out        = (float*)d_out;

    char* ws        = (char*)d_ws;
    int* blockAny   = (int*)ws;
    float* rowSum   = (float*)(ws + 128);
    float* g2       = (float*)(ws + 16384);

    edt_col_scan<<<BH * NTILES, 1024, 0, stream>>>(tgt, g2, blockAny);
    edt_row_loss<<<BH * HH, 256, 0, stream>>>(pred, g2, rowSum);
    finalize<<<1, 256, 0, stream>>>(rowSum, blockAny, out);
}